// Round 6
// baseline (316.908 us; speedup 1.0000x reference)
//
#include <hip/hip_runtime.h>

// SelfAttention: B=4 S=2048 D=1024 H=16 HD=64, causal, fp32 in/out, bf16 MFMA compute.
// R5: isolation round. Attention reverted to the R3-proven structure (paired
// q-tiles {t,31-t}, online max softmax, f2bf packing, grid (16,64)) — the R4
// restructure showed first-vs-replay divergence (race signature) and regressed
// speed. Kept from R4 only the exp2-domain fold: 0.125*log2e baked into Wq,
// exp2 replaces exp (identical math in log2 domain). GEMMs unchanged (m97-style).

typedef __attribute__((ext_vector_type(8))) short short8_t;
typedef __attribute__((ext_vector_type(4))) short short4_t;
typedef __attribute__((ext_vector_type(4))) float float4_t;

constexpr int Bz = 4, Sq = 2048, Dm = 1024, NH = 16, HD = 64;
constexpr int LDSPITCH = 72;

#define GLOAD_LDS16(g, l)                                                      \
  __builtin_amdgcn_global_load_lds(                                            \
      (const __attribute__((address_space(1))) unsigned int*)(g),              \
      (__attribute__((address_space(3))) unsigned int*)(l), 16, 0, 0)

__device__ __forceinline__ unsigned short f2bf(float f) {
  unsigned u = __builtin_bit_cast(unsigned, f);
  u += 0x7fffu + ((u >> 16) & 1u);
  return (unsigned short)(u >> 16);
}

__global__ __launch_bounds__(256) void cast_x_kernel(const float* __restrict__ x,
                                                     unsigned short* __restrict__ xb) {
  size_t i = (size_t)blockIdx.x * 256 + threadIdx.x;
  float4 v = ((const float4*)x)[i];
  ushort4 o;
  o.x = f2bf(v.x); o.y = f2bf(v.y); o.z = f2bf(v.z); o.w = f2bf(v.w);
  ((ushort4*)xb)[i] = o;
}

// W [K=1024][N=1024] fp32 -> WT [N][K] bf16, scaled (Wq carries 0.125*log2e)
__global__ __launch_bounds__(256) void transpose_w_kernel(const float* __restrict__ W,
                                                          unsigned short* __restrict__ WT,
                                                          float scale) {
  __shared__ float tile[64][65];
  int n0 = blockIdx.x * 64, k0 = blockIdx.y * 64;
  int tx = threadIdx.x & 63, ty = threadIdx.x >> 6;
#pragma unroll
  for (int i = 0; i < 16; ++i) {
    int r = i * 4 + ty;
    tile[r][tx] = W[(size_t)(k0 + r) * Dm + n0 + tx];
  }
  __syncthreads();
#pragma unroll
  for (int i = 0; i < 16; ++i) {
    int r = i * 4 + ty;
    WT[(size_t)(n0 + r) * Dm + k0 + tx] = f2bf(tile[tx][r] * scale);
  }
}

// m97-style main loop: 128x128 tile, BK=64, glds width=16, unpadded LDS.
__device__ __forceinline__ void gemm_mainloop(const unsigned short* __restrict__ A,
                                              const unsigned short* __restrict__ BT,
                                              int m0, int n0,
                                              unsigned short* lA, unsigned short* lB,
                                              float4_t acc[4][4]) {
  const int tid = threadIdx.x;
  const int lane = tid & 63, lr = lane & 15, quad = lane >> 4;
  const int wave = tid >> 6;
  const int mw = (wave >> 1) * 64, nw = (wave & 1) * 64;
  const int srow = tid >> 3;
  const int scol = (tid & 7) * 8;
  const unsigned short* ga = A + (size_t)(m0 + srow) * Dm + scol;
  const unsigned short* gb = BT + (size_t)(n0 + srow) * Dm + scol;
  unsigned short* la = lA + tid * 8;
  unsigned short* lb = lB + tid * 8;

  for (int k0 = 0; k0 < Dm; k0 += 64) {
    __syncthreads();
#pragma unroll
    for (int iss = 0; iss < 4; ++iss) {
      GLOAD_LDS16(ga + (size_t)iss * 32 * Dm + k0, la + iss * 32 * 64);
      GLOAD_LDS16(gb + (size_t)iss * 32 * Dm + k0, lb + iss * 32 * 64);
    }
    __syncthreads();
#pragma unroll
    for (int kk = 0; kk < 2; ++kk) {
      short8_t a[4], b[4];
#pragma unroll
      for (int i = 0; i < 4; ++i)
        a[i] = *(const short8_t*)(lA + (mw + i * 16 + lr) * 64 + kk * 32 + quad * 8);
#pragma unroll
      for (int j = 0; j < 4; ++j)
        b[j] = *(const short8_t*)(lB + (nw + j * 16 + lr) * 64 + kk * 32 + quad * 8);
#pragma unroll
      for (int i = 0; i < 4; ++i)
#pragma unroll
        for (int j = 0; j < 4; ++j)
          acc[i][j] = __builtin_amdgcn_mfma_f32_16x16x32_bf16(a[i], b[j], acc[i][j], 0, 0, 0);
    }
  }
}

// QKV projections. Q,K -> [B,H,S,HD]; V -> TRANSPOSED [B,H,HD,S]. grid (8,64,3)
__global__ __launch_bounds__(256) void gemm_qkv_kernel(
    const unsigned short* __restrict__ xb,
    const unsigned short* __restrict__ wqT, const unsigned short* __restrict__ wkT,
    const unsigned short* __restrict__ wvT,
    unsigned short* __restrict__ qb, unsigned short* __restrict__ kb,
    unsigned short* __restrict__ vt) {
  __shared__ unsigned short lA[128 * 64];
  __shared__ unsigned short lB[128 * 64];
  const unsigned short* WT = blockIdx.z == 0 ? wqT : (blockIdx.z == 1 ? wkT : wvT);
  unsigned short* outb = blockIdx.z == 0 ? qb : (blockIdx.z == 1 ? kb : vt);
  bool isV = blockIdx.z == 2;
  int lane = threadIdx.x & 63, wave = threadIdx.x >> 6;
  int lr = lane & 15, quad = lane >> 4;
  int m0 = blockIdx.y * 128, n0 = blockIdx.x * 128;
  int m_base = m0 + (wave >> 1) * 64;
  int n_base = n0 + (wave & 1) * 64;
  float4_t z = {0.f, 0.f, 0.f, 0.f};
  float4_t acc[4][4];
#pragma unroll
  for (int i = 0; i < 4; ++i)
#pragma unroll
    for (int j = 0; j < 4; ++j) acc[i][j] = z;
  gemm_mainloop(xb, WT, m0, n0, lA, lB, acc);
  if (isV) {
#pragma unroll
    for (int i = 0; i < 4; ++i)
#pragma unroll
      for (int j = 0; j < 4; ++j) {
        int m = m_base + i * 16 + quad * 4;
        int n = n_base + j * 16 + lr;
        int b = m >> 11, s = m & (Sq - 1);
        int h = n >> 6, hd = n & (HD - 1);
        ushort4 pk;
        pk.x = f2bf(acc[i][j][0]); pk.y = f2bf(acc[i][j][1]);
        pk.z = f2bf(acc[i][j][2]); pk.w = f2bf(acc[i][j][3]);
        *(ushort4*)(outb + (((size_t)b * NH + h) * HD + hd) * Sq + s) = pk;
      }
  } else {
#pragma unroll
    for (int i = 0; i < 4; ++i)
#pragma unroll
      for (int j = 0; j < 4; ++j)
#pragma unroll
        for (int r = 0; r < 4; ++r) {
          int m = m_base + i * 16 + quad * 4 + r;
          int n = n_base + j * 16 + lr;
          int b = m >> 11, s = m & (Sq - 1);
          int h = n >> 6, hd = n & (HD - 1);
          outb[(((size_t)b * NH + h) * Sq + s) * HD + hd] = f2bf(acc[i][j][r]);
        }
  }
}

// Output projection: ao_bf16 [8192,1024] @ Wo -> fp32 out. grid (8,64)
__global__ __launch_bounds__(256) void gemm_out_kernel(
    const unsigned short* __restrict__ ao, const unsigned short* __restrict__ woT,
    float* __restrict__ out) {
  __shared__ unsigned short lA[128 * 64];
  __shared__ unsigned short lB[128 * 64];
  int lane = threadIdx.x & 63, wave = threadIdx.x >> 6;
  int lr = lane & 15, quad = lane >> 4;
  int m0 = blockIdx.y * 128, n0 = blockIdx.x * 128;
  int m_base = m0 + (wave >> 1) * 64;
  int n_base = n0 + (wave & 1) * 64;
  float4_t z = {0.f, 0.f, 0.f, 0.f};
  float4_t acc[4][4];
#pragma unroll
  for (int i = 0; i < 4; ++i)
#pragma unroll
    for (int j = 0; j < 4; ++j) acc[i][j] = z;
  gemm_mainloop(ao, woT, m0, n0, lA, lB, acc);
#pragma unroll
  for (int i = 0; i < 4; ++i)
#pragma unroll
    for (int j = 0; j < 4; ++j)
#pragma unroll
      for (int r = 0; r < 4; ++r) {
        int m = m_base + i * 16 + quad * 4 + r;
        int n = n_base + j * 16 + lr;
        out[(size_t)m * Dm + n] = acc[i][j][r];
      }
}

// Flash attention (R3-proven structure; exp2-domain, scale folded into Wq).
// grid (16, B*H), block 256 (4 waves). Block does q-tiles {t, 31-t}.
__global__ __launch_bounds__(256) void attn_kernel(
    const unsigned short* __restrict__ qbuf, const unsigned short* __restrict__ kbuf,
    const unsigned short* __restrict__ vtbuf, unsigned short* __restrict__ ao) {
  __shared__ unsigned short lk[64 * LDSPITCH];
  __shared__ unsigned short lv[64 * LDSPITCH];
  int bh = blockIdx.y;
  int wave = threadIdx.x >> 6, lane = threadIdx.x & 63;
  int lcol = lane & 15, quad = lane >> 4;
  const unsigned short* Q = qbuf + (size_t)bh * Sq * HD;
  const unsigned short* K = kbuf + (size_t)bh * Sq * HD;
  const unsigned short* Vt = vtbuf + (size_t)bh * HD * Sq;
  int b = bh >> 4, h = bh & 15;
  int srow = threadIdx.x >> 2;
  int scol = (threadIdx.x & 3) * 16;
  float4_t z = {0.f, 0.f, 0.f, 0.f};

  for (int half = 0; half < 2; ++half) {
    int ti = half == 0 ? (int)blockIdx.x : 31 - (int)blockIdx.x;
    int q0w = ti * 64 + wave * 16;
    int q_global = q0w + lcol;
    short8_t qf0 = *(const short8_t*)(Q + (size_t)(q0w + lcol) * HD + quad * 8);
    short8_t qf1 = *(const short8_t*)(Q + (size_t)(q0w + lcol) * HD + 32 + quad * 8);
    float m_i = -INFINITY, l_i = 0.f;
    float4_t o[4];
#pragma unroll
    for (int f = 0; f < 4; ++f) o[f] = z;

    int nkt = ti + 1;
    for (int kt = 0; kt < nkt; ++kt) {
      int key0 = kt * 64;
      __syncthreads();
      {
        const unsigned short* kg = K + (size_t)(key0 + srow) * HD + scol;
        const unsigned short* vg = Vt + (size_t)srow * Sq + key0 + scol;
        unsigned short* kl = lk + srow * LDSPITCH + scol;
        unsigned short* vl = lv + srow * LDSPITCH + scol;
        *(short8_t*)(kl) = *(const short8_t*)(kg);
        *(short8_t*)(kl + 8) = *(const short8_t*)(kg + 8);
        *(short8_t*)(vl) = *(const short8_t*)(vg);
        *(short8_t*)(vl + 8) = *(const short8_t*)(vg + 8);
      }
      __syncthreads();

      bool need_mask = (key0 + 63 > q0w);
      float s[16];
      float tmax = -INFINITY;
#pragma unroll
      for (int s4 = 0; s4 < 4; ++s4) {
        short8_t kf0 = *(const short8_t*)(lk + (s4 * 16 + lcol) * LDSPITCH + quad * 8);
        short8_t kf1 = *(const short8_t*)(lk + (s4 * 16 + lcol) * LDSPITCH + 32 + quad * 8);
        float4_t st = z;
        st = __builtin_amdgcn_mfma_f32_16x16x32_bf16(kf0, qf0, st, 0, 0, 0);
        st = __builtin_amdgcn_mfma_f32_16x16x32_bf16(kf1, qf1, st, 0, 0, 0);
#pragma unroll
        for (int r = 0; r < 4; ++r) {
          float v = st[r];  // already in log2 domain (scale folded into Wq)
          if (need_mask && (key0 + s4 * 16 + quad * 4 + r > q_global)) v = -INFINITY;
          s[s4 * 4 + r] = v;
          tmax = fmaxf(tmax, v);
        }
      }
      tmax = fmaxf(tmax, __shfl_xor(tmax, 16, 64));
      tmax = fmaxf(tmax, __shfl_xor(tmax, 32, 64));
      float m_new = fmaxf(m_i, tmax);
      float alpha = __builtin_amdgcn_exp2f(m_i - m_new);  // first tile: exp2(-inf)=0
      float psum = 0.f;
      short4_t pf[4];
#pragma unroll
      for (int s4 = 0; s4 < 4; ++s4)
#pragma unroll
        for (int r = 0; r < 4; ++r) {
          float p = __builtin_amdgcn_exp2f(s[s4 * 4 + r] - m_new);
          psum += p;
          pf[s4][r] = (short)f2bf(p);
        }
      psum += __shfl_xor(psum, 16, 64);
      psum += __shfl_xor(psum, 32, 64);
      l_i = l_i * alpha + psum;
      m_i = m_new;
      float at[4];
#pragma unroll
      for (int r = 0; r < 4; ++r) at[r] = __shfl(alpha, quad * 4 + r, 64);
#pragma unroll
      for (int f = 0; f < 4; ++f)
#pragma unroll
        for (int r = 0; r < 4; ++r) o[f][r] *= at[r];
#pragma unroll
      for (int f = 0; f < 4; ++f)
#pragma unroll
        for (int s4 = 0; s4 < 4; ++s4) {
          short4_t vf =
              *(const short4_t*)(lv + (f * 16 + lcol) * LDSPITCH + s4 * 16 + quad * 4);
          o[f] = __builtin_amdgcn_mfma_f32_16x16x16bf16_1k(pf[s4], vf, o[f], 0, 0, 0);
        }
    }

    float lt[4];
#pragma unroll
    for (int r = 0; r < 4; ++r) lt[r] = 1.f / __shfl(l_i, quad * 4 + r, 64);
#pragma unroll
    for (int f = 0; f < 4; ++f)
#pragma unroll
      for (int r = 0; r < 4; ++r) {
        int q = q0w + quad * 4 + r;
        int hd = f * 16 + lcol;
        ao[((size_t)b * Sq + q) * (NH * HD) + h * HD + hd] = f2bf(o[f][r] * lt[r]);
      }
  }
}

extern "C" void kernel_launch(void* const* d_in, const int* in_sizes, int n_in,
                              void* d_out, int out_size, void* d_ws, size_t ws_size,
                              hipStream_t stream) {
  const float* x = (const float*)d_in[0];
  const float* Wq = (const float*)d_in[1];
  const float* Wk = (const float*)d_in[2];
  const float* Wv = (const float*)d_in[3];
  const float* Wo = (const float*)d_in[4];
  float* out = (float*)d_out;

  char* ws = (char*)d_ws;
  size_t off = 0;
  auto carve = [&](size_t bytes) {
    void* p = ws + off;
    off += (bytes + 255) & ~(size_t)255;
    return p;
  };
  const size_t xe = (size_t)Bz * Sq * Dm;
  const size_t we = (size_t)Dm * Dm;
  unsigned short* xb = (unsigned short*)carve(xe * 2);
  unsigned short* wqT = (unsigned short*)carve(we * 2);
  unsigned short* wkT = (unsigned short*)carve(we * 2);
  unsigned short* wvT = (unsigned short*)carve(we * 2);
  unsigned short* woT = (unsigned short*)carve(we * 2);
  unsigned short* qb = (unsigned short*)carve(xe * 2);
  unsigned short* kb = (unsigned short*)carve(xe * 2);
  unsigned short* vt = (unsigned short*)carve(xe * 2);
  unsigned short* ao = (unsigned short*)carve(xe * 2);
  (void)ws_size;

  const float kQScale = 0.125f * 1.4426950408889634f;  // 1/sqrt(64) * log2(e)
  cast_x_kernel<<<xe / 4 / 256, 256, 0, stream>>>(x, xb);
  transpose_w_kernel<<<dim3(16, 16), 256, 0, stream>>>(Wq, wqT, kQScale);
  transpose_w_kernel<<<dim3(16, 16), 256, 0, stream>>>(Wk, wkT, 1.0f);
  transpose_w_kernel<<<dim3(16, 16), 256, 0, stream>>>(Wv, wvT, 1.0f);
  transpose_w_kernel<<<dim3(16, 16), 256, 0, stream>>>(Wo, woT, 1.0f);
  gemm_qkv_kernel<<<dim3(8, 64, 3), 256, 0, stream>>>(xb, wqT, wkT, wvT, qb, kb, vt);
  attn_kernel<<<dim3(16, Bz * NH), 256, 0, stream>>>(qb, kb, vt, ao);
  gemm_out_kernel<<<dim3(8, 64), 256, 0, stream>>>(ao, woT, out);
}